// Round 1
// baseline (514.819 us; speedup 1.0000x reference)
//
#include <hip/hip_runtime.h>
#include <math.h>

#define BINS 10
#define REPL 16   // LDS histogram replicas to spread same-address atomic contention

struct WS {
    double       sum[BINS];   // global per-bin weighted-BCE sums
    unsigned int cnt[BINS];   // global per-bin valid counts (exact)
};

__device__ __forceinline__ void accum_one(float x, float t, float w, int r,
                                          float* s_sum, unsigned int* s_cnt) {
    if (!(w > 0.0f)) return;
    float ax  = fabsf(x);
    float e   = __expf(-ax);                         // exp(-|x|) in (0,1]
    float inv = __builtin_amdgcn_rcpf(1.0f + e);     // 1/(1+e)
    float sig = (x >= 0.0f) ? inv : (1.0f - inv);    // sigmoid(x)
    float g   = fabsf(sig - t);                      // in [0,1)
    int idx   = (int)(g * 10.0f);                    // floor (g >= 0)
    idx = idx > (BINS - 1) ? (BINS - 1) : (idx < 0 ? 0 : idx);
    // stable BCE-with-logits
    float bce = fmaxf(x, 0.0f) - x * t + __logf(1.0f + e);
    atomicAdd(&s_sum[idx * REPL + r], bce);
    atomicAdd(&s_cnt[idx * REPL + r], 1u);
}

__global__ __launch_bounds__(256) void ghmc_main(const float* __restrict__ pred,
                                                 const float* __restrict__ target,
                                                 const float* __restrict__ lw,
                                                 WS* __restrict__ ws,
                                                 long long total) {
    __shared__ float        s_sum[BINS * REPL];
    __shared__ unsigned int s_cnt[BINS * REPL];
    const int tid = threadIdx.x;
    for (int i = tid; i < BINS * REPL; i += blockDim.x) { s_sum[i] = 0.0f; s_cnt[i] = 0u; }
    __syncthreads();

    const int r = tid & (REPL - 1);
    const long long nvec   = total >> 2;                         // float4 chunks
    const long long stride = (long long)gridDim.x * blockDim.x;

    for (long long i = (long long)blockIdx.x * blockDim.x + tid; i < nvec; i += stride) {
        float4 p = reinterpret_cast<const float4*>(pred)[i];
        float4 t = reinterpret_cast<const float4*>(target)[i];
        float4 w = reinterpret_cast<const float4*>(lw)[i];
        float px[4] = {p.x, p.y, p.z, p.w};
        float tx[4] = {t.x, t.y, t.z, t.w};
        float wx[4] = {w.x, w.y, w.z, w.w};
#pragma unroll
        for (int k = 0; k < 4; ++k)
            accum_one(px[k], tx[k], wx[k], r, s_sum, s_cnt);
    }

    // scalar tail (total % 4), handled by block 0
    const long long base = nvec << 2;
    const int rem = (int)(total - base);
    if (blockIdx.x == 0 && tid < rem)
        accum_one(pred[base + tid], target[base + tid], lw[base + tid], r, s_sum, s_cnt);

    __syncthreads();
    if (tid < BINS) {
        float s = 0.0f; unsigned int c = 0u;
#pragma unroll
        for (int j = 0; j < REPL; ++j) { s += s_sum[tid * REPL + j]; c += s_cnt[tid * REPL + j]; }
        if (c) {
            atomicAdd(&ws->sum[tid], (double)s);
            atomicAdd(&ws->cnt[tid], c);
        }
    }
}

__global__ void ghmc_finalize(const WS* __restrict__ ws, float* __restrict__ out) {
    if (threadIdx.x == 0 && blockIdx.x == 0) {
        double acc = 0.0;
        int n = 0;
        for (int b = 0; b < BINS; ++b) {
            unsigned int c = ws->cnt[b];
            if (c) { acc += ws->sum[b] / (double)c; ++n; }
        }
        double denom = (n > 0) ? (double)n : 1.0;
        out[0] = (float)(acc / denom);   // LOSS_WEIGHT == 1.0
    }
}

extern "C" void kernel_launch(void* const* d_in, const int* in_sizes, int n_in,
                              void* d_out, int out_size, void* d_ws, size_t ws_size,
                              hipStream_t stream) {
    const float* pred   = (const float*)d_in[0];
    const float* target = (const float*)d_in[1];
    const float* lw     = (const float*)d_in[2];
    float* out = (float*)d_out;
    WS* ws = (WS*)d_ws;
    const long long total = (long long)in_sizes[0];

    hipMemsetAsync(d_ws, 0, sizeof(WS), stream);

    const int threads = 256;
    const int blocks  = 2048;   // 524288 threads, ~20 float4 iters each
    ghmc_main<<<blocks, threads, 0, stream>>>(pred, target, lw, ws, total);
    ghmc_finalize<<<1, 64, 0, stream>>>(ws, out);
}

// Round 2
// 458.313 us; speedup vs baseline: 1.1233x; 1.1233x over previous
//
#include <hip/hip_runtime.h>
#include <math.h>

#define BINS 10
#define NBLOCKS 2048
#define THREADS 256

struct Partial {
    float        sum[BINS];
    unsigned int cnt[BINS];
};

__device__ __forceinline__ void accum_one(float x, float t, float w,
                                          float (&s)[BINS], unsigned int (&c)[BINS]) {
    const bool valid = (w > 0.0f);
    float ax  = fabsf(x);
    float e   = __expf(-ax);                          // exp(-|x|) in (0,1]
    float inv = __builtin_amdgcn_rcpf(1.0f + e);      // 1/(1+e)
    float sig = (x >= 0.0f) ? inv : (1.0f - inv);     // sigmoid(x)
    float g   = fabsf(sig - t);                       // in [0,1)
    int idx   = (int)(g * 10.0f);
    idx = idx > (BINS - 1) ? (BINS - 1) : idx;
    float bce = fmaxf(x, 0.0f) - x * t + __logf(1.0f + e);
    bce = valid ? bce : 0.0f;
    const unsigned int one = valid ? 1u : 0u;
#pragma unroll
    for (int b = 0; b < BINS; ++b) {                  // branchless register histogram
        const bool m = (idx == b);
        s[b] += m ? bce : 0.0f;
        c[b] += m ? one : 0u;
    }
}

__global__ __launch_bounds__(THREADS) void ghmc_main(const float* __restrict__ pred,
                                                     const float* __restrict__ target,
                                                     const float* __restrict__ lw,
                                                     Partial* __restrict__ part,
                                                     long long total) {
    float        s[BINS];
    unsigned int c[BINS];
#pragma unroll
    for (int b = 0; b < BINS; ++b) { s[b] = 0.0f; c[b] = 0u; }

    const int tid = threadIdx.x;
    const long long nvec   = total >> 2;                       // float4 chunks
    const long long stride = (long long)gridDim.x * THREADS;

    for (long long i = (long long)blockIdx.x * THREADS + tid; i < nvec; i += stride) {
        float4 p = reinterpret_cast<const float4*>(pred)[i];
        float4 t = reinterpret_cast<const float4*>(target)[i];
        float4 w = reinterpret_cast<const float4*>(lw)[i];
        accum_one(p.x, t.x, w.x, s, c);
        accum_one(p.y, t.y, w.y, s, c);
        accum_one(p.z, t.z, w.z, s, c);
        accum_one(p.w, t.w, w.w, s, c);
    }

    // scalar tail (total % 4): block 0 only
    const long long base = nvec << 2;
    const int rem = (int)(total - base);
    if (blockIdx.x == 0 && tid < rem)
        accum_one(pred[base + tid], target[base + tid], lw[base + tid], s, c);

    // wave-64 butterfly reduce (20 values)
#pragma unroll
    for (int b = 0; b < BINS; ++b) {
#pragma unroll
        for (int off = 32; off; off >>= 1) {
            s[b] += __shfl_xor(s[b], off, 64);
            c[b] += __shfl_xor(c[b], off, 64);
        }
    }

    __shared__ float        ls[THREADS / 64][BINS];
    __shared__ unsigned int lc[THREADS / 64][BINS];
    const int wid  = tid >> 6;
    const int lane = tid & 63;
    if (lane == 0) {
#pragma unroll
        for (int b = 0; b < BINS; ++b) { ls[wid][b] = s[b]; lc[wid][b] = c[b]; }
    }
    __syncthreads();

    if (tid < BINS) {
        float sb = 0.0f; unsigned int cb = 0u;
#pragma unroll
        for (int w2 = 0; w2 < THREADS / 64; ++w2) { sb += ls[w2][tid]; cb += lc[w2][tid]; }
        part[blockIdx.x].sum[tid] = sb;   // plain store — no atomics, no memset needed
        part[blockIdx.x].cnt[tid] = cb;
    }
}

__global__ __launch_bounds__(THREADS) void ghmc_finalize(const Partial* __restrict__ part,
                                                         float* __restrict__ out,
                                                         int nblocks) {
    double             acc[BINS];
    unsigned long long cn[BINS];
#pragma unroll
    for (int b = 0; b < BINS; ++b) { acc[b] = 0.0; cn[b] = 0ull; }

    const int tid = threadIdx.x;
    for (int i = tid; i < nblocks; i += THREADS) {
#pragma unroll
        for (int b = 0; b < BINS; ++b) {
            acc[b] += (double)part[i].sum[b];
            cn[b]  += (unsigned long long)part[i].cnt[b];
        }
    }

#pragma unroll
    for (int b = 0; b < BINS; ++b) {
#pragma unroll
        for (int off = 32; off; off >>= 1) {
            acc[b] += __shfl_xor(acc[b], off, 64);
            cn[b]  += __shfl_xor(cn[b], off, 64);
        }
    }

    __shared__ double             lds_s[THREADS / 64][BINS];
    __shared__ unsigned long long lds_c[THREADS / 64][BINS];
    const int wid  = tid >> 6;
    const int lane = tid & 63;
    if (lane == 0) {
#pragma unroll
        for (int b = 0; b < BINS; ++b) { lds_s[wid][b] = acc[b]; lds_c[wid][b] = cn[b]; }
    }
    __syncthreads();

    if (tid == 0) {
        double loss = 0.0;
        int n = 0;
        for (int b = 0; b < BINS; ++b) {
            double sb = 0.0; unsigned long long cb = 0ull;
            for (int w2 = 0; w2 < THREADS / 64; ++w2) { sb += lds_s[w2][b]; cb += lds_c[w2][b]; }
            if (cb) { loss += sb / (double)cb; ++n; }
        }
        double denom = (n > 0) ? (double)n : 1.0;
        out[0] = (float)(loss / denom);   // LOSS_WEIGHT == 1.0; tot cancels algebraically
    }
}

extern "C" void kernel_launch(void* const* d_in, const int* in_sizes, int n_in,
                              void* d_out, int out_size, void* d_ws, size_t ws_size,
                              hipStream_t stream) {
    const float* pred   = (const float*)d_in[0];
    const float* target = (const float*)d_in[1];
    const float* lw     = (const float*)d_in[2];
    float* out = (float*)d_out;
    Partial* part = (Partial*)d_ws;
    const long long total = (long long)in_sizes[0];

    ghmc_main<<<NBLOCKS, THREADS, 0, stream>>>(pred, target, lw, part, total);
    ghmc_finalize<<<1, THREADS, 0, stream>>>(part, out, NBLOCKS);
}

// Round 3
// 449.004 us; speedup vs baseline: 1.1466x; 1.0207x over previous
//
#include <hip/hip_runtime.h>
#include <math.h>

#define BINS 10
#define NBLOCKS 2048
#define THREADS 256

struct Partial {
    float        sum[BINS];
    unsigned int cnt[BINS];
};

// Per-element: bce into per-thread register sums (3 VALU/bin: cmp+cndmask+add),
// counts via wave-uniform ballot+popcount on the SCALAR pipe (2 SALU/bin).
__device__ __forceinline__ void accum_one(float x, float t, float w,
                                          float (&s)[BINS], unsigned int (&c)[BINS]) {
    float ax  = __builtin_fabsf(x);
    float e   = __expf(-ax);                      // exp(-|x|) in (0,1]
    float opd = 1.0f + e;
    float inv = __builtin_amdgcn_rcpf(opd);       // sigmoid(|x|)
    float sig = (x >= 0.0f) ? inv : (1.0f - inv); // sigmoid(x)
    float g   = __builtin_fabsf(sig - t);         // in [0,1) for this data
    int   idx = (int)(g * 10.0f);                 // trunc == floor (g >= 0)
    idx = idx > (BINS - 1) ? (BINS - 1) : idx;
    idx = (w > 0.0f) ? idx : -1;                  // invalid -> matches no bin
    float bce = fmaxf(x, 0.0f) - x * t + __logf(opd);
#pragma unroll
    for (int b = 0; b < BINS; ++b) {
        bool m = (idx == b);
        s[b] += m ? bce : 0.0f;                               // 1 cmp + cndmask + add
        c[b] += (unsigned int)__popcll(__ballot(m));          // scalar: s_bcnt1 + s_add
    }
}

__global__ __launch_bounds__(THREADS) void ghmc_main(const float* __restrict__ pred,
                                                     const float* __restrict__ target,
                                                     const float* __restrict__ lw,
                                                     Partial* __restrict__ part,
                                                     long long total) {
    float        s[BINS];
    unsigned int c[BINS];
#pragma unroll
    for (int b = 0; b < BINS; ++b) { s[b] = 0.0f; c[b] = 0u; }

    const int tid = threadIdx.x;
    const long long nvec   = total >> 2;                      // float4 chunks
    const long long stride = (long long)gridDim.x * THREADS;
    const float4* __restrict__ P = reinterpret_cast<const float4*>(pred);
    const float4* __restrict__ T = reinterpret_cast<const float4*>(target);
    const float4* __restrict__ W = reinterpret_cast<const float4*>(lw);

    long long i = (long long)blockIdx.x * THREADS + tid;
    // unroll-by-2 over grid stride: 6 independent dwordx4 loads in flight
    for (; i + stride < nvec; i += 2 * stride) {
        float4 p0 = P[i];          float4 t0 = T[i];          float4 w0 = W[i];
        float4 p1 = P[i + stride]; float4 t1 = T[i + stride]; float4 w1 = W[i + stride];
        accum_one(p0.x, t0.x, w0.x, s, c);
        accum_one(p0.y, t0.y, w0.y, s, c);
        accum_one(p0.z, t0.z, w0.z, s, c);
        accum_one(p0.w, t0.w, w0.w, s, c);
        accum_one(p1.x, t1.x, w1.x, s, c);
        accum_one(p1.y, t1.y, w1.y, s, c);
        accum_one(p1.z, t1.z, w1.z, s, c);
        accum_one(p1.w, t1.w, w1.w, s, c);
    }
    for (; i < nvec; i += stride) {
        float4 p = P[i]; float4 t = T[i]; float4 w = W[i];
        accum_one(p.x, t.x, w.x, s, c);
        accum_one(p.y, t.y, w.y, s, c);
        accum_one(p.z, t.z, w.z, s, c);
        accum_one(p.w, t.w, w.w, s, c);
    }

    // scalar tail (total % 4): block 0 only (empty for this shape)
    const long long base = nvec << 2;
    const int rem = (int)(total - base);
    if (blockIdx.x == 0 && tid < rem)
        accum_one(pred[base + tid], target[base + tid], lw[base + tid], s, c);

    // sums: wave-64 butterfly; counts: already wave-uniform (ballot path)
#pragma unroll
    for (int b = 0; b < BINS; ++b) {
#pragma unroll
        for (int off = 32; off; off >>= 1)
            s[b] += __shfl_xor(s[b], off, 64);
    }

    __shared__ float        ls[THREADS / 64][BINS];
    __shared__ unsigned int lc[THREADS / 64][BINS];
    const int wid  = tid >> 6;
    const int lane = tid & 63;
    if (lane == 0) {
#pragma unroll
        for (int b = 0; b < BINS; ++b) { ls[wid][b] = s[b]; lc[wid][b] = c[b]; }
    }
    __syncthreads();

    if (tid < BINS) {
        float sb = 0.0f; unsigned int cb = 0u;
#pragma unroll
        for (int w2 = 0; w2 < THREADS / 64; ++w2) { sb += ls[w2][tid]; cb += lc[w2][tid]; }
        part[blockIdx.x].sum[tid] = sb;   // plain store — no atomics
        part[blockIdx.x].cnt[tid] = cb;
    }
}

__global__ __launch_bounds__(THREADS) void ghmc_finalize(const Partial* __restrict__ part,
                                                         float* __restrict__ out,
                                                         int nblocks) {
    double             acc[BINS];
    unsigned long long cn[BINS];
#pragma unroll
    for (int b = 0; b < BINS; ++b) { acc[b] = 0.0; cn[b] = 0ull; }

    const int tid = threadIdx.x;
    for (int i = tid; i < nblocks; i += THREADS) {
#pragma unroll
        for (int b = 0; b < BINS; ++b) {
            acc[b] += (double)part[i].sum[b];
            cn[b]  += (unsigned long long)part[i].cnt[b];
        }
    }

#pragma unroll
    for (int b = 0; b < BINS; ++b) {
#pragma unroll
        for (int off = 32; off; off >>= 1) {
            acc[b] += __shfl_xor(acc[b], off, 64);
            cn[b]  += __shfl_xor(cn[b], off, 64);
        }
    }

    __shared__ double             lds_s[THREADS / 64][BINS];
    __shared__ unsigned long long lds_c[THREADS / 64][BINS];
    const int wid  = tid >> 6;
    const int lane = tid & 63;
    if (lane == 0) {
#pragma unroll
        for (int b = 0; b < BINS; ++b) { lds_s[wid][b] = acc[b]; lds_c[wid][b] = cn[b]; }
    }
    __syncthreads();

    if (tid == 0) {
        double loss = 0.0;
        int n = 0;
        for (int b = 0; b < BINS; ++b) {
            double sb = 0.0; unsigned long long cb = 0ull;
            for (int w2 = 0; w2 < THREADS / 64; ++w2) { sb += lds_s[w2][b]; cb += lds_c[w2][b]; }
            if (cb) { loss += sb / (double)cb; ++n; }
        }
        double denom = (n > 0) ? (double)n : 1.0;
        out[0] = (float)(loss / denom);   // LOSS_WEIGHT == 1.0; tot cancels algebraically
    }
}

extern "C" void kernel_launch(void* const* d_in, const int* in_sizes, int n_in,
                              void* d_out, int out_size, void* d_ws, size_t ws_size,
                              hipStream_t stream) {
    const float* pred   = (const float*)d_in[0];
    const float* target = (const float*)d_in[1];
    const float* lw     = (const float*)d_in[2];
    float* out = (float*)d_out;
    Partial* part = (Partial*)d_ws;
    const long long total = (long long)in_sizes[0];

    ghmc_main<<<NBLOCKS, THREADS, 0, stream>>>(pred, target, lw, part, total);
    ghmc_finalize<<<1, THREADS, 0, stream>>>(part, out, NBLOCKS);
}